// Round 8
// baseline (4490.685 us; speedup 1.0000x reference)
//
#include <hip/hip_runtime.h>
#include <hip/hip_bf16.h>
#include <stdint.h>

// ---------------- problem constants ----------------
constexpr int Hh  = 768;     // hidden
constexpr int Ss  = 256;     // seq len
constexpr int Bb  = 32;      // batch
constexpr int G4  = 4 * Hh;  // 3072 gate cols
constexpr int MR  = Bb * Ss; // 8192 rows of the big GEMM
constexpr int NWGL = 96;     // LSTM workgroups per layer
constexpr int UPW8 = Hh / NWGL;  // 8 hidden units per WG
constexpr int LCW  = 4 * UPW8;   // 32 gate cols per WG
constexpr int WPAD = Hh + 8;     // padded weight row: stride 1552B == 16B mod 128B
constexpr int PB   = Bb + 2;     // padded pool staging row (34)
constexpr int KH   = Hh / 2;     // pool k-half (384)

typedef short bf16x8 __attribute__((ext_vector_type(8)));
typedef float f32x4  __attribute__((ext_vector_type(4)));
typedef float f32x2  __attribute__((ext_vector_type(2)));

__device__ __forceinline__ unsigned short f2bf(float f) {
  union { float f; uint32_t u; } v; v.f = f;
  uint32_t u = v.u;
  return (unsigned short)((u + 0x7FFFu + ((u >> 16) & 1u)) >> 16); // RNE
}
__device__ __forceinline__ float bf2f(unsigned short h) {
  union { uint32_t u; float f; } v; v.u = ((uint32_t)h) << 16; return v.f;
}

// ---------------- embedding gather + bf16 cast ----------------
__global__ __launch_bounds__(256) void k_embed(const int* __restrict__ ids,
                                               const float* __restrict__ table,
                                               unsigned short* __restrict__ x_bf) {
  int row = blockIdx.x;                 // b*S+s
  int id  = ids[row];
  const float* src = table + (size_t)id * Hh;
  unsigned short* dst = x_bf + (size_t)row * Hh;
  for (int j = threadIdx.x; j < Hh; j += 256) dst[j] = f2bf(src[j]);
}

// ---------------- fp32 -> bf16 cast (4 elems/thread) ----------------
__global__ __launch_bounds__(256) void k_cast(const float* __restrict__ src,
                                              unsigned short* __restrict__ dst, int n4) {
  int i = blockIdx.x * 256 + threadIdx.x;
  if (i < n4) {
    float4 v = ((const float4*)src)[i];
    uint2 o;
    o.x = (uint32_t)f2bf(v.x) | ((uint32_t)f2bf(v.y) << 16);
    o.y = (uint32_t)f2bf(v.z) | ((uint32_t)f2bf(v.w) << 16);
    ((uint2*)dst)[i] = o;
  }
}

// ---------------- MFMA bf16 TN GEMM -> per-(s,wg) packed pre-gate layout -----
__global__ __launch_bounds__(256) void k_gemm_bt(const unsigned short* __restrict__ A,
                                                 const unsigned short* __restrict__ Bw,
                                                 unsigned short* __restrict__ g2,
                                                 const float* __restrict__ bias1,
                                                 const float* __restrict__ bias2,
                                                 int M, int N, int K) {
  constexpr int BM = 128, BN = 128, BK = 64;
  __shared__ unsigned short Asm[BM * BK];
  __shared__ unsigned short Bsm[BN * BK];
  const int tid = threadIdx.x, lane = tid & 63, wave = tid >> 6;
  const int m0 = blockIdx.x * BM, n0 = blockIdx.y * BN;
  const int wm = (wave & 1) * 64, wn = (wave >> 1) * 64;

  f32x4 acc[4][4];
  #pragma unroll
  for (int a = 0; a < 4; ++a)
    #pragma unroll
    for (int b = 0; b < 4; ++b) acc[a][b] = (f32x4){0.f, 0.f, 0.f, 0.f};

  const int nk = K / BK;
  bf16x8 ar[4], br[4];
  #pragma unroll
  for (int r = 0; r < 4; ++r) {
    int fb = r * 4096 + tid * 16;
    int row = fb >> 7;
    int kb  = (fb >> 4) & 7;
    ar[r] = *(const bf16x8*)(A  + (size_t)(m0 + row) * K + kb * 8);
    br[r] = *(const bf16x8*)(Bw + (size_t)(n0 + row) * K + kb * 8);
  }
  for (int it = 0; it < nk; ++it) {
    __syncthreads();
    #pragma unroll
    for (int r = 0; r < 4; ++r) {
      int fb = r * 4096 + tid * 16;
      int row = fb >> 7;
      int kb  = (fb >> 4) & 7;
      int sb  = kb ^ (row & 7);
      *(bf16x8*)((char*)Asm + row * 128 + sb * 16) = ar[r];
      *(bf16x8*)((char*)Bsm + row * 128 + sb * 16) = br[r];
    }
    __syncthreads();
    if (it + 1 < nk) {
      int k0 = (it + 1) * BK;
      #pragma unroll
      for (int r = 0; r < 4; ++r) {
        int fb = r * 4096 + tid * 16;
        int row = fb >> 7;
        int kb  = (fb >> 4) & 7;
        ar[r] = *(const bf16x8*)(A  + (size_t)(m0 + row) * K + k0 + kb * 8);
        br[r] = *(const bf16x8*)(Bw + (size_t)(n0 + row) * K + k0 + kb * 8);
      }
    }
    #pragma unroll
    for (int kk = 0; kk < 2; ++kk) {
      bf16x8 af[4], bfr[4];
      #pragma unroll
      for (int mi = 0; mi < 4; ++mi) {
        int row = wm + mi * 16 + (lane & 15);
        int kb  = kk * 4 + (lane >> 4);
        int sb  = kb ^ (row & 7);
        af[mi] = *(const bf16x8*)((const char*)Asm + row * 128 + sb * 16);
      }
      #pragma unroll
      for (int ni = 0; ni < 4; ++ni) {
        int row = wn + ni * 16 + (lane & 15);
        int kb  = kk * 4 + (lane >> 4);
        int sb  = kb ^ (row & 7);
        bfr[ni] = *(const bf16x8*)((const char*)Bsm + row * 128 + sb * 16);
      }
      #pragma unroll
      for (int mi = 0; mi < 4; ++mi)
        #pragma unroll
        for (int ni = 0; ni < 4; ++ni)
          acc[mi][ni] = __builtin_amdgcn_mfma_f32_16x16x32_bf16(af[mi], bfr[ni], acc[mi][ni], 0, 0, 0);
    }
  }
  #pragma unroll
  for (int mi = 0; mi < 4; ++mi)
    #pragma unroll
    for (int ni = 0; ni < 4; ++ni)
      #pragma unroll
      for (int r = 0; r < 4; ++r) {
        int row = m0 + wm + mi * 16 + (lane >> 4) * 4 + r;   // = b*256 + s
        int n   = n0 + wn + ni * 16 + (lane & 15);           // gate col
        int bb = row >> 8, ss = row & 255;
        int gi = n / Hh, u = n - gi * Hh;
        int wg = u >> 3, lc = gi * 8 + (u & 7);
        float v = acc[mi][ni][r] + bias1[n] + bias2[n];
        g2[(((size_t)ss * NWGL + wg) * Bb + bb) * LCW + lc] = f2bf(v);
      }
}

// ---- poison-poll load of 24 x 64B-strided 16B chunks (one h row per lane) ----
// Values are bf16 tanh-bounded: 0xFFFF (NaN) can only be the poison pattern.
// 8B agent-scope atomic loads bypass stale L1/L2; each 8B store is atomic, so
// checking one half per 8B suffices.
__device__ __forceinline__ void poll_load24(const unsigned short* base,
                                            unsigned long long (&lo)[24],
                                            unsigned long long (&hi)[24]) {
  const unsigned long long* pp = (const unsigned long long*)base;
  for (;;) {
    #pragma unroll
    for (int kk = 0; kk < 24; ++kk) {
      lo[kk] = __hip_atomic_load(pp + kk * 8,     __ATOMIC_RELAXED, __HIP_MEMORY_SCOPE_AGENT);
      hi[kk] = __hip_atomic_load(pp + kk * 8 + 1, __ATOMIC_RELAXED, __HIP_MEMORY_SCOPE_AGENT);
    }
    bool bad = false;
    #pragma unroll
    for (int kk = 0; kk < 24; ++kk) {
      bad = bad || (((unsigned)lo[kk] & 0xFFFFu) == 0xFFFFu);
      bad = bad || (((unsigned)hi[kk] & 0xFFFFu) == 0xFFFFu);
    }
    if (__all(!bad)) return;
    __builtin_amdgcn_s_sleep(1);
  }
}

// ---------------- fused 2-layer LSTM: barrier-free poison-poll dataflow ------
// WGs 0..95: layer-1; 96..191: layer-2. No flags, no vmcnt waits, no barriers
// in the time loop. hseq1/hseq2 pre-poisoned to 0xFFFF; producers fire relaxed
// 8B agent stores; consumers poll the data itself.
__global__ __launch_bounds__(128) void k_lstm2(
    const unsigned short* __restrict__ g2,
    const unsigned short* __restrict__ w_hh0b,
    const unsigned short* __restrict__ w_ih1b,
    const unsigned short* __restrict__ w_hh1b,
    const float* __restrict__ b_ih1,
    const float* __restrict__ b_hh1,
    unsigned short* __restrict__ hseq1,
    unsigned short* __restrict__ hseq2) {
  __shared__ __align__(16) unsigned short Whh[LCW * WPAD];
  __shared__ __align__(16) unsigned short Wih[LCW * WPAD];
  __shared__ __align__(16) unsigned short hbuf[2][16][8];

  const int wgid = blockIdx.x;
  const int tid = threadIdx.x;
  const int lane = tid & 63, w = tid >> 6;     // w in {0,1}

  const int layer = wgid >= NWGL;
  const int wg = layer ? wgid - NWGL : wgid;
  const int u0 = wg * UPW8;

  // stage weight slices into padded LDS rows
  {
    const unsigned short* src = layer ? w_hh1b : w_hh0b;
    for (int cch = tid; cch < LCW * 96; cch += 128) {
      int row = cch / 96, kc = cch - row * 96;
      int gi = row >> 3, u = row & 7;
      *(bf16x8*)&Whh[row * WPAD + kc * 8] =
          *(const bf16x8*)(src + (size_t)(gi * Hh + u0 + u) * Hh + kc * 8);
    }
    if (layer) {
      for (int cch = tid; cch < LCW * 96; cch += 128) {
        int row = cch / 96, kc = cch - row * 96;
        int gi = row >> 3, u = row & 7;
        *(bf16x8*)&Wih[row * WPAD + kc * 8] =
            *(const bf16x8*)(w_ih1b + (size_t)(gi * Hh + u0 + u) * Hh + kc * 8);
      }
    }
  }
  __syncthreads();   // weights staged (only barrier in this kernel)

  const int l15 = lane & 15, kq = lane >> 4;
  const int brow = w * 16 + l15;               // this wave's A row (batch)
  const bool lo8 = (l15 < 8);

  const float k1 = lo8 ? 2.f : 1.f;            // nt1 lanes: g (tanh) if lo8 else o
  const float m1 = lo8 ? 2.f : 1.f;
  const float d1 = lo8 ? -1.f : 0.f;

  float bl[2] = {0.f, 0.f};
  if (layer) {
    #pragma unroll
    for (int nt = 0; nt < 2; ++nt) {
      int c = nt * 16 + l15;
      int gcol = (c >> 3) * Hh + u0 + (c & 7);
      bl[nt] = b_ih1[gcol] + b_hh1[gcol];
    }
  }

  unsigned short gc[2][4];
  if (!layer) {
    const unsigned short* grow = g2 + ((size_t)0 * NWGL + wg) * (Bb * LCW);
    #pragma unroll
    for (int nt = 0; nt < 2; ++nt)
      #pragma unroll
      for (int r = 0; r < 4; ++r)
        gc[nt][r] = grow[(w * 16 + kq * 4 + r) * LCW + nt * 16 + l15];  // t=0
  }
  float cc[4] = {0.f, 0.f, 0.f, 0.f};
  unsigned short* hout = layer ? hseq2 : hseq1;

  unsigned long long alo[24], ahi[24];

  for (int t = 0; t < Ss; ++t) {
    f32x4 aW[2][2], aI[2][2];
    #pragma unroll
    for (int nt = 0; nt < 2; ++nt) {
      aW[nt][0] = (f32x4){0.f,0.f,0.f,0.f}; aW[nt][1] = (f32x4){0.f,0.f,0.f,0.f};
      aI[nt][0] = (f32x4){0.f,0.f,0.f,0.f}; aI[nt][1] = (f32x4){0.f,0.f,0.f,0.f};
    }

    if (t > 0) {
      // own-layer recurrence (the critical chain): poll h[t-1], then GEMM
      poll_load24(hout + ((size_t)(t - 1) * Bb + brow) * Hh + kq * 8, alo, ahi);
      #pragma unroll
      for (int nt = 0; nt < 2; ++nt) {
        const int c = nt * 16 + l15;
        #pragma unroll
        for (int kk = 0; kk < 24; ++kk) {
          union { unsigned long long q[2]; bf16x8 v; } u;
          u.q[0] = alo[kk]; u.q[1] = ahi[kk];
          bf16x8 bfr = *(const bf16x8*)&Whh[c * WPAD + kk * 32 + kq * 8];
          aW[nt][kk & 1] = __builtin_amdgcn_mfma_f32_16x16x32_bf16(u.v, bfr, aW[nt][kk & 1], 0, 0, 0);
        }
      }
    }
    if (layer) {
      // h1[t] input (usually already published): poll, then GEMM
      poll_load24(hseq1 + ((size_t)t * Bb + brow) * Hh + kq * 8, alo, ahi);
      #pragma unroll
      for (int nt = 0; nt < 2; ++nt) {
        const int c = nt * 16 + l15;
        #pragma unroll
        for (int kk = 0; kk < 24; ++kk) {
          union { unsigned long long q[2]; bf16x8 v; } u;
          u.q[0] = alo[kk]; u.q[1] = ahi[kk];
          bf16x8 bfr = *(const bf16x8*)&Wih[c * WPAD + kk * 32 + kq * 8];
          aI[nt][kk & 1] = __builtin_amdgcn_mfma_f32_16x16x32_bf16(u.v, bfr, aI[nt][kk & 1], 0, 0, 0);
        }
      }
    }

    // ---- activations (in-register) ----
    float act0[4], act1[4];
    #pragma unroll
    for (int r = 0; r < 4; ++r) {
      float v0 = aW[0][0][r] + aW[0][1][r] + aI[0][0][r] + aI[0][1][r]
               + (layer ? bl[0] : bf2f(gc[0][r]));
      act0[r] = 1.f / (1.f + __expf(-v0));                   // i or f: sigmoid
      float v1 = aW[1][0][r] + aW[1][1][r] + aI[1][0][r] + aI[1][1][r]
               + (layer ? bl[1] : bf2f(gc[1][r]));
      act1[r] = m1 / (1.f + __expf(-k1 * v1)) + d1;          // g: tanh, o: sigmoid
    }

    // ---- pointwise c/h via lane^8 shuffle ----
    #pragma unroll
    for (int r = 0; r < 4; ++r) {
      float p0 = __shfl_xor(act0[r], 8);
      float p1 = __shfl_xor(act1[r], 8);
      float iv = lo8 ? act0[r] : p0;
      float fv = lo8 ? p0 : act0[r];
      float gv = lo8 ? act1[r] : p1;
      float ov = lo8 ? p1 : act1[r];
      float cn = fv * cc[r] + iv * gv;
      cc[r] = cn;
      float e = __expf(-2.f * cn);
      float hv = ov * (1.f - e) / (1.f + e);
      if (lo8) hbuf[w][kq * 4 + r][l15] = f2bf(hv);
    }
    asm volatile("s_waitcnt lgkmcnt(0)" ::: "memory");   // wave's hbuf writes done

    // ---- publish h: fire-and-forget relaxed 8B agent stores (no vmcnt) ----
    if (lane < 16) {
      const unsigned long long* hb = (const unsigned long long*)&hbuf[w][lane][0];
      unsigned long long x0 = hb[0], x1 = hb[1];
      unsigned long long* hp =
          (unsigned long long*)(hout + ((size_t)t * Bb + (w * 16 + lane)) * Hh + u0);
      __hip_atomic_store(hp + 0, x0, __ATOMIC_RELAXED, __HIP_MEMORY_SCOPE_AGENT);
      __hip_atomic_store(hp + 1, x1, __ATOMIC_RELAXED, __HIP_MEMORY_SCOPE_AGENT);
    }

    // ---- prefetch next-step pre-gates ----
    if (!layer && t + 1 < Ss) {
      const unsigned short* grow = g2 + ((size_t)(t + 1) * NWGL + wg) * (Bb * LCW);
      #pragma unroll
      for (int nt = 0; nt < 2; ++nt)
        #pragma unroll
        for (int r = 0; r < 4; ++r)
          gc[nt][r] = grow[(w * 16 + kq * 4 + r) * LCW + nt * 16 + l15];
    }
  }
}

// ---------------- pool partial over a k-half: grid (Ss, 2) -------------------
__global__ __launch_bounds__(256) void k_pool_partial(const unsigned short* __restrict__ hseq2,
                                                      const float* __restrict__ pw,
                                                      float* __restrict__ partial) {
  __shared__ unsigned short osm[KH * PB];  // [k][b], padded
  const int tid = threadIdx.x;
  const int s = blockIdx.x, half = blockIdx.y;
  const int k0 = half * KH;
  for (int b = 0; b < Bb; ++b) {
    const unsigned short* src = hseq2 + ((size_t)s * Bb + b) * Hh + k0;
    for (int k = tid; k < KH; k += 256) osm[k * PB + b] = src[k];
  }
  __syncthreads();
  f32x2 acc[16][3];
  #pragma unroll
  for (int bp = 0; bp < 16; ++bp)
    #pragma unroll
    for (int j = 0; j < 3; ++j) acc[bp][j] = (f32x2){0.f, 0.f};
  const float* pbase = pw + (size_t)s * Hh * Hh + (size_t)k0 * Hh;
  #pragma unroll 4
  for (int k = 0; k < KH; ++k) {
    float w0 = pbase[(size_t)k * Hh + tid];
    float w1 = pbase[(size_t)k * Hh + 256 + tid];
    float w2 = pbase[(size_t)k * Hh + 512 + tid];
    const uint32_t* orow = (const uint32_t*)&osm[k * PB];
    #pragma unroll
    for (int bp = 0; bp < 16; ++bp) {
      uint32_t pv = orow[bp];
      f32x2 ov;
      ov.x = __uint_as_float(pv << 16);
      ov.y = __uint_as_float(pv & 0xffff0000u);
      acc[bp][0] += ov * w0;
      acc[bp][1] += ov * w1;
      acc[bp][2] += ov * w2;
    }
  }
  float* pout = partial + (size_t)(s * 2 + half) * (Bb * Hh);
  #pragma unroll
  for (int bp = 0; bp < 16; ++bp)
    #pragma unroll
    for (int j = 0; j < 3; ++j) {
      pout[(size_t)(bp * 2 + 0) * Hh + j * 256 + tid] = acc[bp][j].x;
      pout[(size_t)(bp * 2 + 1) * Hh + j * 256 + tid] = acc[bp][j].y;
    }
}

// ---------------- pool reduce over 512 partials ----------------
__global__ __launch_bounds__(256) void k_pool_reduce(const float* __restrict__ partial,
                                                     const float* __restrict__ pool_b,
                                                     float* __restrict__ seq_out) {
  int i = blockIdx.x * 256 + threadIdx.x;
  float acc = pool_b[i % Hh];
  #pragma unroll 8
  for (int t = 0; t < 2 * Ss; ++t) acc += partial[(size_t)t * (Bb * Hh) + i];
  seq_out[i] = acc;
}

// ---------------- entity masked max + logits ----------------
__global__ __launch_bounds__(256) void k_entity_logits(const unsigned short* __restrict__ hseq2,
                                                       const float* __restrict__ seq_out,
                                                       const int* __restrict__ entity_ids,
                                                       const float* __restrict__ lin_w,
                                                       const float* __restrict__ lin_b,
                                                       float* __restrict__ logits_ws,
                                                       float* __restrict__ dlogits) {
  const int b = blockIdx.x, tid = threadIdx.x;
  float m0 = -1e30f, m1 = -1e30f, m2 = -1e30f;
  for (int s = 0; s < Ss; ++s) {
    bool e = entity_ids[b * Ss + s] == 1;
    const unsigned short* row = hseq2 + ((size_t)s * Bb + b) * Hh;
    float v0 = bf2f(row[tid]);
    float v1 = bf2f(row[256 + tid]);
    float v2 = bf2f(row[512 + tid]);
    v0 = e ? v0 : 0.f; v1 = e ? v1 : 0.f; v2 = e ? v2 : 0.f;
    m0 = fmaxf(m0, v0); m1 = fmaxf(m1, v1); m2 = fmaxf(m2, v2);
  }
  __shared__ float red[512];
  float p0 = 0.f, p1 = 0.f;
  float mm[3] = {m0, m1, m2};
  #pragma unroll
  for (int j = 0; j < 3; ++j) {
    int n = j * 256 + tid;
    float bo = fmaxf(mm[j], seq_out[b * Hh + n]);
    p0 += bo * lin_w[n * 2 + 0];
    p1 += bo * lin_w[n * 2 + 1];
  }
  red[tid] = p0; red[256 + tid] = p1;
  __syncthreads();
  for (int off = 128; off > 0; off >>= 1) {
    if (tid < off) { red[tid] += red[tid + off]; red[256 + tid] += red[256 + tid + off]; }
    __syncthreads();
  }
  if (tid == 0) {
    float l0 = red[0] + lin_b[0], l1 = red[256] + lin_b[1];
    logits_ws[b * 2] = l0; logits_ws[b * 2 + 1] = l1;
    dlogits[b * 2] = l0;  dlogits[b * 2 + 1] = l1;
  }
}

// ---------------- BCEWithLogits mean loss ----------------
__global__ void k_loss(const float* __restrict__ logits, const int* __restrict__ lab,
                       float* __restrict__ dout) {
  __shared__ float red[64];
  int i = threadIdx.x;
  float l = logits[i];
  float y = (float)lab[i];
  red[i] = fmaxf(l, 0.f) - l * y + log1pf(__expf(-fabsf(l)));
  __syncthreads();
  for (int off = 32; off > 0; off >>= 1) {
    if (i < off) red[i] += red[i + off];
    __syncthreads();
  }
  if (i == 0) dout[0] = red[0] * (1.f / 64.f);
}

// ---------------- launcher ----------------
extern "C" void kernel_launch(void* const* d_in, const int* in_sizes, int n_in,
                              void* d_out, int out_size, void* d_ws, size_t ws_size,
                              hipStream_t stream) {
  const int*   input_ids  = (const int*)d_in[0];
  const int*   seq_label  = (const int*)d_in[3];
  const int*   entity_ids = (const int*)d_in[4];
  const float* embed      = (const float*)d_in[5];
  const float* w_ih0      = (const float*)d_in[6];
  const float* w_hh0      = (const float*)d_in[7];
  const float* b_ih0      = (const float*)d_in[8];
  const float* b_hh0      = (const float*)d_in[9];
  const float* w_ih1      = (const float*)d_in[10];
  const float* w_hh1      = (const float*)d_in[11];
  const float* b_ih1      = (const float*)d_in[12];
  const float* b_hh1      = (const float*)d_in[13];
  const float* pool_w     = (const float*)d_in[14];
  const float* pool_b     = (const float*)d_in[15];
  const float* lin_w      = (const float*)d_in[16];
  const float* lin_b      = (const float*)d_in[17];
  float* out = (float*)d_out;

  const size_t SZ_XO = (size_t)Bb * Ss * Hh * 2;   // 12.58 MB
  const size_t SZ_W  = (size_t)G4 * Hh * 2;        //  4.72 MB
  const size_t SZ_G  = (size_t)Bb * Ss * G4 * 2;   // 50.33 MB
  char* ws = (char*)d_ws;
  size_t off = 0;
  unsigned short* x_bf   = (unsigned short*)(ws + off); off += SZ_XO;
  unsigned short* wb_ih0 = (unsigned short*)(ws + off); off += SZ_W;
  unsigned short* wb_hh0 = (unsigned short*)(ws + off); off += SZ_W;
  unsigned short* wb_ih1 = (unsigned short*)(ws + off); off += SZ_W;
  unsigned short* wb_hh1 = (unsigned short*)(ws + off); off += SZ_W;
  unsigned short* g2     = (unsigned short*)(ws + off); off += SZ_G;
  unsigned short* hseq1  = (unsigned short*)(ws + off); off += SZ_XO;
  unsigned short* hseq2  = (unsigned short*)(ws + off); off += SZ_XO;
  float*          seq_out= (float*)(ws + off);          off += (size_t)Bb * Hh * 4;
  float*          logits = (float*)(ws + off);          off += 1024;
  // partial (50.3 MB fp32) aliases x_bf..g2 (81.8 MB): dead once k_lstm2 done.
  float*          partial = (float*)ws;

  // poison h sequences: 0xFF bytes -> bf16 0xFFFF (NaN), impossible as tanh output
  hipMemsetAsync(hseq1, 0xFF, SZ_XO, stream);
  hipMemsetAsync(hseq2, 0xFF, SZ_XO, stream);

  k_embed<<<Bb * Ss, 256, 0, stream>>>(input_ids, embed, x_bf);
  int n4 = (G4 * Hh) / 4;
  int cgrid = (n4 + 255) / 256;
  k_cast<<<cgrid, 256, 0, stream>>>(w_ih0, wb_ih0, n4);
  k_cast<<<cgrid, 256, 0, stream>>>(w_hh0, wb_hh0, n4);
  k_cast<<<cgrid, 256, 0, stream>>>(w_ih1, wb_ih1, n4);
  k_cast<<<cgrid, 256, 0, stream>>>(w_hh1, wb_hh1, n4);

  dim3 ggrid(MR / 128, G4 / 128);
  k_gemm_bt<<<ggrid, 256, 0, stream>>>(x_bf, wb_ih0, g2, b_ih0, b_hh0, MR, G4, Hh);

  k_lstm2<<<2 * NWGL, 128, 0, stream>>>(g2, wb_hh0, wb_ih1, wb_hh1,
                                        b_ih1, b_hh1, hseq1, hseq2);

  dim3 pgrid(Ss, 2);
  k_pool_partial<<<pgrid, 256, 0, stream>>>(hseq2, pool_w, partial);
  k_pool_reduce<<<(Bb * Hh) / 256, 256, 0, stream>>>(partial, pool_b, seq_out);
  k_entity_logits<<<Bb, 256, 0, stream>>>(hseq2, seq_out, entity_ids, lin_w, lin_b,
                                          logits, out + 1);
  k_loss<<<1, 64, 0, stream>>>(logits, seq_label, out);
}

// Round 9
// 2750.241 us; speedup vs baseline: 1.6328x; 1.6328x over previous
//
#include <hip/hip_runtime.h>
#include <hip/hip_bf16.h>
#include <stdint.h>

// ---------------- problem constants ----------------
constexpr int Hh  = 768;     // hidden
constexpr int Ss  = 256;     // seq len
constexpr int Bb  = 32;      // batch
constexpr int G4  = 4 * Hh;  // 3072 gate cols
constexpr int MR  = Bb * Ss; // 8192 rows of the big GEMM
constexpr int NWGL = 96;     // LSTM workgroups per layer
constexpr int UPW8 = Hh / NWGL;  // 8 hidden units per WG
constexpr int LCW  = 4 * UPW8;   // 32 gate cols per WG
constexpr int WPAD = Hh + 8;     // padded weight row: stride 1552B == 16B mod 128B
constexpr int CPT  = 256;        // counter dwords per step (16 buckets x 16-dword stride)
constexpr int PB   = 40;         // pool staging row pad: 80B rows, 16B-aligned for b128
constexpr int NCH  = 3;          // pool n-chunks (3 x 256 cols)

typedef short bf16x8 __attribute__((ext_vector_type(8)));
typedef float f32x4  __attribute__((ext_vector_type(4)));
typedef float f32x2  __attribute__((ext_vector_type(2)));
typedef uint32_t u32x4 __attribute__((ext_vector_type(4)));

__device__ __forceinline__ unsigned short f2bf(float f) {
  union { float f; uint32_t u; } v; v.f = f;
  uint32_t u = v.u;
  return (unsigned short)((u + 0x7FFFu + ((u >> 16) & 1u)) >> 16); // RNE
}
__device__ __forceinline__ float bf2f(unsigned short h) {
  union { uint32_t u; float f; } v; v.u = ((uint32_t)h) << 16; return v.f;
}

// ---------------- embedding gather + bf16 cast ----------------
__global__ __launch_bounds__(256) void k_embed(const int* __restrict__ ids,
                                               const float* __restrict__ table,
                                               unsigned short* __restrict__ x_bf) {
  int row = blockIdx.x;                 // b*S+s
  int id  = ids[row];
  const float* src = table + (size_t)id * Hh;
  unsigned short* dst = x_bf + (size_t)row * Hh;
  for (int j = threadIdx.x; j < Hh; j += 256) dst[j] = f2bf(src[j]);
}

// ---------------- fp32 -> bf16 cast (4 elems/thread) ----------------
__global__ __launch_bounds__(256) void k_cast(const float* __restrict__ src,
                                              unsigned short* __restrict__ dst, int n4) {
  int i = blockIdx.x * 256 + threadIdx.x;
  if (i < n4) {
    float4 v = ((const float4*)src)[i];
    uint2 o;
    o.x = (uint32_t)f2bf(v.x) | ((uint32_t)f2bf(v.y) << 16);
    o.y = (uint32_t)f2bf(v.z) | ((uint32_t)f2bf(v.w) << 16);
    ((uint2*)dst)[i] = o;
  }
}

// ---------------- MFMA bf16 TN GEMM -> per-(s,wg) packed pre-gate layout -----
__global__ __launch_bounds__(256) void k_gemm_bt(const unsigned short* __restrict__ A,
                                                 const unsigned short* __restrict__ Bw,
                                                 unsigned short* __restrict__ g2,
                                                 const float* __restrict__ bias1,
                                                 const float* __restrict__ bias2,
                                                 int M, int N, int K) {
  constexpr int BM = 128, BN = 128, BK = 64;
  __shared__ unsigned short Asm[BM * BK];
  __shared__ unsigned short Bsm[BN * BK];
  const int tid = threadIdx.x, lane = tid & 63, wave = tid >> 6;
  const int m0 = blockIdx.x * BM, n0 = blockIdx.y * BN;
  const int wm = (wave & 1) * 64, wn = (wave >> 1) * 64;

  f32x4 acc[4][4];
  #pragma unroll
  for (int a = 0; a < 4; ++a)
    #pragma unroll
    for (int b = 0; b < 4; ++b) acc[a][b] = (f32x4){0.f, 0.f, 0.f, 0.f};

  const int nk = K / BK;
  bf16x8 ar[4], br[4];
  #pragma unroll
  for (int r = 0; r < 4; ++r) {
    int fb = r * 4096 + tid * 16;
    int row = fb >> 7;
    int kb  = (fb >> 4) & 7;
    ar[r] = *(const bf16x8*)(A  + (size_t)(m0 + row) * K + kb * 8);
    br[r] = *(const bf16x8*)(Bw + (size_t)(n0 + row) * K + kb * 8);
  }
  for (int it = 0; it < nk; ++it) {
    __syncthreads();
    #pragma unroll
    for (int r = 0; r < 4; ++r) {
      int fb = r * 4096 + tid * 16;
      int row = fb >> 7;
      int kb  = (fb >> 4) & 7;
      int sb  = kb ^ (row & 7);
      *(bf16x8*)((char*)Asm + row * 128 + sb * 16) = ar[r];
      *(bf16x8*)((char*)Bsm + row * 128 + sb * 16) = br[r];
    }
    __syncthreads();
    if (it + 1 < nk) {
      int k0 = (it + 1) * BK;
      #pragma unroll
      for (int r = 0; r < 4; ++r) {
        int fb = r * 4096 + tid * 16;
        int row = fb >> 7;
        int kb  = (fb >> 4) & 7;
        ar[r] = *(const bf16x8*)(A  + (size_t)(m0 + row) * K + k0 + kb * 8);
        br[r] = *(const bf16x8*)(Bw + (size_t)(n0 + row) * K + k0 + kb * 8);
      }
    }
    #pragma unroll
    for (int kk = 0; kk < 2; ++kk) {
      bf16x8 af[4], bfr[4];
      #pragma unroll
      for (int mi = 0; mi < 4; ++mi) {
        int row = wm + mi * 16 + (lane & 15);
        int kb  = kk * 4 + (lane >> 4);
        int sb  = kb ^ (row & 7);
        af[mi] = *(const bf16x8*)((const char*)Asm + row * 128 + sb * 16);
      }
      #pragma unroll
      for (int ni = 0; ni < 4; ++ni) {
        int row = wn + ni * 16 + (lane & 15);
        int kb  = kk * 4 + (lane >> 4);
        int sb  = kb ^ (row & 7);
        bfr[ni] = *(const bf16x8*)((const char*)Bsm + row * 128 + sb * 16);
      }
      #pragma unroll
      for (int mi = 0; mi < 4; ++mi)
        #pragma unroll
        for (int ni = 0; ni < 4; ++ni)
          acc[mi][ni] = __builtin_amdgcn_mfma_f32_16x16x32_bf16(af[mi], bfr[ni], acc[mi][ni], 0, 0, 0);
    }
  }
  #pragma unroll
  for (int mi = 0; mi < 4; ++mi)
    #pragma unroll
    for (int ni = 0; ni < 4; ++ni)
      #pragma unroll
      for (int r = 0; r < 4; ++r) {
        int row = m0 + wm + mi * 16 + (lane >> 4) * 4 + r;   // = b*256 + s
        int n   = n0 + wn + ni * 16 + (lane & 15);           // gate col
        int bb = row >> 8, ss = row & 255;
        int gi = n / Hh, u = n - gi * Hh;
        int wg = u >> 3, lc = gi * 8 + (u & 7);
        float v = acc[mi][ni][r] + bias1[n] + bias2[n];
        g2[(((size_t)ss * NWGL + wg) * Bb + bb) * LCW + lc] = f2bf(v);
      }
}

// ---------------- fused 2-layer LSTM, bucketed-counter sync (R7) -------------
// cnt1[t*256 + j*16] j=0..15: each bucket reaches 12 (6 WGs x 2 waves).
// L1 WG step t: wait cnt1[t-1] full. L2 WG step t: wait cnt1[t] AND cnt2[t-1].
__global__ __launch_bounds__(128) void k_lstm2(
    const unsigned short* __restrict__ g2,
    const unsigned short* __restrict__ w_hh0b,
    const unsigned short* __restrict__ w_ih1b,
    const unsigned short* __restrict__ w_hh1b,
    const float* __restrict__ b_ih1,
    const float* __restrict__ b_hh1,
    unsigned short* __restrict__ hseq1,
    unsigned short* __restrict__ hseq2,
    unsigned int* __restrict__ sync) {
  __shared__ __align__(16) unsigned short Whh[LCW * WPAD];
  __shared__ __align__(16) unsigned short Wih[LCW * WPAD];
  __shared__ __align__(16) unsigned short hbuf[2][16][8];

  const int wgid = blockIdx.x;
  const int tid = threadIdx.x;
  const int lane = tid & 63, w = tid >> 6;     // w in {0,1}
  unsigned int* cnt1 = sync;
  unsigned int* cnt2 = sync + Ss * CPT;

  const int layer = wgid >= NWGL;
  const int wg = layer ? wgid - NWGL : wgid;
  const int u0 = wg * UPW8;
  const int bkt = wg & 15;

  // stage weight slices into padded LDS rows
  {
    const unsigned short* src = layer ? w_hh1b : w_hh0b;
    for (int cch = tid; cch < LCW * 96; cch += 128) {
      int row = cch / 96, kc = cch - row * 96;
      int gi = row >> 3, u = row & 7;
      *(bf16x8*)&Whh[row * WPAD + kc * 8] =
          *(const bf16x8*)(src + (size_t)(gi * Hh + u0 + u) * Hh + kc * 8);
    }
    if (layer) {
      for (int cch = tid; cch < LCW * 96; cch += 128) {
        int row = cch / 96, kc = cch - row * 96;
        int gi = row >> 3, u = row & 7;
        *(bf16x8*)&Wih[row * WPAD + kc * 8] =
            *(const bf16x8*)(w_ih1b + (size_t)(gi * Hh + u0 + u) * Hh + kc * 8);
      }
    }
  }
  __syncthreads();

  const int l15 = lane & 15, kq = lane >> 4;
  const int brow = w * 16 + l15;               // this wave's A row (batch)
  const bool lo8 = (l15 < 8);

  const float k1 = lo8 ? 2.f : 1.f;            // nt1 lanes: g (tanh) if lo8 else o
  const float m1 = lo8 ? 2.f : 1.f;
  const float d1 = lo8 ? -1.f : 0.f;

  float bl[2] = {0.f, 0.f};
  if (layer) {
    #pragma unroll
    for (int nt = 0; nt < 2; ++nt) {
      int c = nt * 16 + l15;
      int gcol = (c >> 3) * Hh + u0 + (c & 7);
      bl[nt] = b_ih1[gcol] + b_hh1[gcol];
    }
  }

  unsigned short gc[2][4];
  if (!layer) {
    const unsigned short* grow = g2 + ((size_t)0 * NWGL + wg) * (Bb * LCW);
    #pragma unroll
    for (int nt = 0; nt < 2; ++nt)
      #pragma unroll
      for (int r = 0; r < 4; ++r)
        gc[nt][r] = grow[(w * 16 + kq * 4 + r) * LCW + nt * 16 + l15];  // t=0
  }
  float cc[4] = {0.f, 0.f, 0.f, 0.f};
  unsigned short* hout = layer ? hseq2 : hseq1;
  unsigned int* mycnt = layer ? cnt2 : cnt1;

  for (int t = 0; t < Ss; ++t) {
    // ---- single poll loop per step (wave 0 only; lanes partition conditions) ----
    if (layer) {
      if (w == 0) {
        const unsigned int* b1 = cnt1 + (size_t)t * CPT;
        const unsigned int* b2 = cnt2 + (size_t)(t - 1) * CPT;
        const bool needOwn = (t > 0);
        for (;;) {
          unsigned v = 12;
          if (lane < 16)
            v = __hip_atomic_load(b1 + lane * 16, __ATOMIC_RELAXED, __HIP_MEMORY_SCOPE_AGENT);
          else if (lane < 32 && needOwn)
            v = __hip_atomic_load(b2 + (lane - 16) * 16, __ATOMIC_RELAXED, __HIP_MEMORY_SCOPE_AGENT);
          if (__all(v >= 12u)) break;
          __builtin_amdgcn_s_sleep(1);
        }
      }
      __syncthreads();
      asm volatile("" ::: "memory");
    } else if (t > 0) {
      if (w == 0) {
        const unsigned int* b1 = cnt1 + (size_t)(t - 1) * CPT;
        for (;;) {
          unsigned v = 12;
          if (lane < 16)
            v = __hip_atomic_load(b1 + lane * 16, __ATOMIC_RELAXED, __HIP_MEMORY_SCOPE_AGENT);
          if (__all(v >= 12u)) break;
          __builtin_amdgcn_s_sleep(1);
        }
      }
      __syncthreads();
      asm volatile("" ::: "memory");
    }

    // ---- gate GEMMs (separate acc chains for the two operands) ----
    f32x4 aI[2][2], aW[2][2];
    #pragma unroll
    for (int nt = 0; nt < 2; ++nt) {
      aI[nt][0] = (f32x4){0.f,0.f,0.f,0.f}; aI[nt][1] = (f32x4){0.f,0.f,0.f,0.f};
      aW[nt][0] = (f32x4){0.f,0.f,0.f,0.f}; aW[nt][1] = (f32x4){0.f,0.f,0.f,0.f};
    }
    if (layer) {
      const unsigned short* ap = hseq1 + ((size_t)t * Bb + brow) * Hh + kq * 8;
      bf16x8 areg[24];
      #pragma unroll
      for (int kk = 0; kk < 24; ++kk) areg[kk] = *(const bf16x8*)(ap + kk * 32);
      #pragma unroll
      for (int nt = 0; nt < 2; ++nt) {
        const int c = nt * 16 + l15;
        #pragma unroll
        for (int kk = 0; kk < 24; ++kk) {
          bf16x8 bfr = *(const bf16x8*)&Wih[c * WPAD + kk * 32 + kq * 8];
          aI[nt][kk & 1] = __builtin_amdgcn_mfma_f32_16x16x32_bf16(areg[kk], bfr, aI[nt][kk & 1], 0, 0, 0);
        }
      }
    }
    if (t > 0) {
      const unsigned short* ap = hout + ((size_t)(t - 1) * Bb + brow) * Hh + kq * 8;
      bf16x8 areg[24];
      #pragma unroll
      for (int kk = 0; kk < 24; ++kk) areg[kk] = *(const bf16x8*)(ap + kk * 32);
      #pragma unroll
      for (int nt = 0; nt < 2; ++nt) {
        const int c = nt * 16 + l15;
        #pragma unroll
        for (int kk = 0; kk < 24; ++kk) {
          bf16x8 bfr = *(const bf16x8*)&Whh[c * WPAD + kk * 32 + kq * 8];
          aW[nt][kk & 1] = __builtin_amdgcn_mfma_f32_16x16x32_bf16(areg[kk], bfr, aW[nt][kk & 1], 0, 0, 0);
        }
      }
    }

    // ---- activations (in-register) ----
    float act0[4], act1[4];
    #pragma unroll
    for (int r = 0; r < 4; ++r) {
      float v0 = aI[0][0][r] + aI[0][1][r] + aW[0][0][r] + aW[0][1][r]
               + (layer ? bl[0] : bf2f(gc[0][r]));
      act0[r] = 1.f / (1.f + __expf(-v0));                   // i or f: sigmoid
      float v1 = aI[1][0][r] + aI[1][1][r] + aW[1][0][r] + aW[1][1][r]
               + (layer ? bl[1] : bf2f(gc[1][r]));
      act1[r] = m1 / (1.f + __expf(-k1 * v1)) + d1;          // g: tanh, o: sigmoid
    }

    // ---- pointwise c/h via lane^8 shuffle ----
    #pragma unroll
    for (int r = 0; r < 4; ++r) {
      float p0 = __shfl_xor(act0[r], 8);
      float p1 = __shfl_xor(act1[r], 8);
      float iv = lo8 ? act0[r] : p0;
      float fv = lo8 ? p0 : act0[r];
      float gv = lo8 ? act1[r] : p1;
      float ov = lo8 ? p1 : act1[r];
      float cn = fv * cc[r] + iv * gv;
      cc[r] = cn;
      float e = __expf(-2.f * cn);
      float hv = ov * (1.f - e) / (1.f + e);
      if (lo8) hbuf[w][kq * 4 + r][l15] = f2bf(hv);
    }
    asm volatile("s_waitcnt lgkmcnt(0)" ::: "memory");   // wave's hbuf writes done

    // ---- publish h (16 lanes x 16B); vmcnt; per-wave bucket add ----
    if (lane < 16) {
      const unsigned long long* hb = (const unsigned long long*)&hbuf[w][lane][0];
      unsigned long long x0 = hb[0], x1 = hb[1];
      unsigned long long* hp =
          (unsigned long long*)(hout + ((size_t)t * Bb + (w * 16 + lane)) * Hh + u0);
      __hip_atomic_store(hp + 0, x0, __ATOMIC_RELAXED, __HIP_MEMORY_SCOPE_AGENT);
      __hip_atomic_store(hp + 1, x1, __ATOMIC_RELAXED, __HIP_MEMORY_SCOPE_AGENT);
    }
    asm volatile("s_waitcnt vmcnt(0)" ::: "memory");     // h acked at LLC
    if (lane == 0) {
      unsigned int* cp = mycnt + (size_t)t * CPT + bkt * 16;
      (void)__hip_atomic_fetch_add(cp, 1u, __ATOMIC_RELAXED, __HIP_MEMORY_SCOPE_AGENT);
    }

    // ---- prefetch next-step pre-gates (off the publish path) ----
    if (!layer && t + 1 < Ss) {
      const unsigned short* grow = g2 + ((size_t)(t + 1) * NWGL + wg) * (Bb * LCW);
      #pragma unroll
      for (int nt = 0; nt < 2; ++nt)
        #pragma unroll
        for (int r = 0; r < 4; ++r)
          gc[nt][r] = grow[(w * 16 + kq * 4 + r) * LCW + nt * 16 + l15];
    }
  }
}

// ---------------- pool partial, n-split: grid (Ss, NCH) ----------------------
// partial[(s*NCH+nc)][b][nn] = sum_k h2[s][b][k] * pw[(s*H+k)][nc*256+nn]
__global__ __launch_bounds__(256) void k_pool_partial(const unsigned short* __restrict__ hseq2,
                                                      const float* __restrict__ pw,
                                                      float* __restrict__ partial) {
  __shared__ __align__(16) unsigned short osm[Hh * PB];  // [k][b], 80B rows (16B-aligned)
  const int tid = threadIdx.x;
  const int s = blockIdx.x, nc = blockIdx.y;
  // stage h2[s] transposed to k-major
  for (int b = 0; b < Bb; ++b) {
    const unsigned short* src = hseq2 + ((size_t)s * Bb + b) * Hh;
    for (int k = tid; k < Hh; k += 256) osm[k * PB + b] = src[k];
  }
  __syncthreads();
  f32x2 acc[16];
  #pragma unroll
  for (int bp = 0; bp < 16; ++bp) acc[bp] = (f32x2){0.f, 0.f};
  const float* pbase = pw + (size_t)s * Hh * Hh + nc * 256 + tid;
  #pragma unroll 4
  for (int k = 0; k < Hh; ++k) {
    float wv = pbase[(size_t)k * Hh];
    // 32 batch h-values: 4 x b128 same-address broadcast reads (conflict-free)
    u32x4 h0 = *(const u32x4*)&osm[k * PB + 0];
    u32x4 h1 = *(const u32x4*)&osm[k * PB + 8];
    u32x4 h2 = *(const u32x4*)&osm[k * PB + 16];
    u32x4 h3 = *(const u32x4*)&osm[k * PB + 24];
    uint32_t hw[16] = {h0[0],h0[1],h0[2],h0[3], h1[0],h1[1],h1[2],h1[3],
                       h2[0],h2[1],h2[2],h2[3], h3[0],h3[1],h3[2],h3[3]};
    #pragma unroll
    for (int bp = 0; bp < 16; ++bp) {
      uint32_t pv = hw[bp];
      f32x2 ov;
      ov.x = __uint_as_float(pv << 16);
      ov.y = __uint_as_float(pv & 0xffff0000u);
      acc[bp] += ov * wv;
    }
  }
  float* pout = partial + (size_t)(s * NCH + nc) * (Bb * 256);
  #pragma unroll
  for (int bp = 0; bp < 16; ++bp) {
    pout[(size_t)(bp * 2 + 0) * 256 + tid] = acc[bp].x;
    pout[(size_t)(bp * 2 + 1) * 256 + tid] = acc[bp].y;
  }
}

// ---------------- pool reduce over Ss partial chunks ----------------
// out (b, n): nc = n>>8, nn = n&255; sum_s partial[(s*NCH+nc)][b][nn]
__global__ __launch_bounds__(256) void k_pool_reduce(const float* __restrict__ partial,
                                                     const float* __restrict__ pool_b,
                                                     float* __restrict__ seq_out) {
  int i = blockIdx.x * 256 + threadIdx.x;   // b*768+n
  int b = i / Hh, n = i - b * Hh;
  int nchunk = n >> 8, nn = n & 255;
  float acc = pool_b[n];
  const float* p = partial + (size_t)nchunk * (Bb * 256) + b * 256 + nn;
  #pragma unroll 8
  for (int t = 0; t < Ss; ++t) acc += p[(size_t)t * NCH * (Bb * 256)];
  seq_out[i] = acc;
}

// ---------------- entity masked max + logits ----------------
__global__ __launch_bounds__(256) void k_entity_logits(const unsigned short* __restrict__ hseq2,
                                                       const float* __restrict__ seq_out,
                                                       const int* __restrict__ entity_ids,
                                                       const float* __restrict__ lin_w,
                                                       const float* __restrict__ lin_b,
                                                       float* __restrict__ logits_ws,
                                                       float* __restrict__ dlogits) {
  const int b = blockIdx.x, tid = threadIdx.x;
  float m0 = -1e30f, m1 = -1e30f, m2 = -1e30f;
  for (int s = 0; s < Ss; ++s) {
    bool e = entity_ids[b * Ss + s] == 1;
    const unsigned short* row = hseq2 + ((size_t)s * Bb + b) * Hh;
    float v0 = bf2f(row[tid]);
    float v1 = bf2f(row[256 + tid]);
    float v2 = bf2f(row[512 + tid]);
    v0 = e ? v0 : 0.f; v1 = e ? v1 : 0.f; v2 = e ? v2 : 0.f;
    m0 = fmaxf(m0, v0); m1 = fmaxf(m1, v1); m2 = fmaxf(m2, v2);
  }
  __shared__ float red[512];
  float p0 = 0.f, p1 = 0.f;
  float mm[3] = {m0, m1, m2};
  #pragma unroll
  for (int j = 0; j < 3; ++j) {
    int n = j * 256 + tid;
    float bo = fmaxf(mm[j], seq_out[b * Hh + n]);
    p0 += bo * lin_w[n * 2 + 0];
    p1 += bo * lin_w[n * 2 + 1];
  }
  red[tid] = p0; red[256 + tid] = p1;
  __syncthreads();
  for (int off = 128; off > 0; off >>= 1) {
    if (tid < off) { red[tid] += red[tid + off]; red[256 + tid] += red[256 + tid + off]; }
    __syncthreads();
  }
  if (tid == 0) {
    float l0 = red[0] + lin_b[0], l1 = red[256] + lin_b[1];
    logits_ws[b * 2] = l0; logits_ws[b * 2 + 1] = l1;
    dlogits[b * 2] = l0;  dlogits[b * 2 + 1] = l1;
  }
}

// ---------------- BCEWithLogits mean loss ----------------
__global__ void k_loss(const float* __restrict__ logits, const int* __restrict__ lab,
                       float* __restrict__ dout) {
  __shared__ float red[64];
  int i = threadIdx.x;
  float l = logits[i];
  float y = (float)lab[i];
  red[i] = fmaxf(l, 0.f) - l * y + log1pf(__expf(-fabsf(l)));
  __syncthreads();
  for (int off = 32; off > 0; off >>= 1) {
    if (i < off) red[i] += red[i + off];
    __syncthreads();
  }
  if (i == 0) dout[0] = red[0] * (1.f / 64.f);
}

// ---------------- launcher ----------------
extern "C" void kernel_launch(void* const* d_in, const int* in_sizes, int n_in,
                              void* d_out, int out_size, void* d_ws, size_t ws_size,
                              hipStream_t stream) {
  const int*   input_ids  = (const int*)d_in[0];
  const int*   seq_label  = (const int*)d_in[3];
  const int*   entity_ids = (const int*)d_in[4];
  const float* embed      = (const float*)d_in[5];
  const float* w_ih0      = (const float*)d_in[6];
  const float* w_hh0      = (const float*)d_in[7];
  const float* b_ih0      = (const float*)d_in[8];
  const float* b_hh0      = (const float*)d_in[9];
  const float* w_ih1      = (const float*)d_in[10];
  const float* w_hh1      = (const float*)d_in[11];
  const float* b_ih1      = (const float*)d_in[12];
  const float* b_hh1      = (const float*)d_in[13];
  const float* pool_w     = (const float*)d_in[14];
  const float* pool_b     = (const float*)d_in[15];
  const float* lin_w      = (const float*)d_in[16];
  const float* lin_b      = (const float*)d_in[17];
  float* out = (float*)d_out;

  const size_t SZ_XO = (size_t)Bb * Ss * Hh * 2;   // 12.58 MB
  const size_t SZ_W  = (size_t)G4 * Hh * 2;        //  4.72 MB
  const size_t SZ_G  = (size_t)Bb * Ss * G4 * 2;   // 50.33 MB
  const size_t SZ_SY = (size_t)2 * Ss * CPT * 4;   // 512 KB counters
  char* ws = (char*)d_ws;
  size_t off = 0;
  unsigned short* x_bf   = (unsigned short*)(ws + off); off += SZ_XO;
  unsigned short* wb_ih0 = (unsigned short*)(ws + off); off += SZ_W;
  unsigned short* wb_hh0 = (unsigned short*)(ws + off); off += SZ_W;
  unsigned short* wb_ih1 = (unsigned short*)(ws + off); off += SZ_W;
  unsigned short* wb_hh1 = (unsigned short*)(ws + off); off += SZ_W;
  unsigned short* g2     = (unsigned short*)(ws + off); off += SZ_G;
  unsigned short* hseq1  = (unsigned short*)(ws + off); off += SZ_XO;
  unsigned short* hseq2  = (unsigned short*)(ws + off); off += SZ_XO;
  float*          seq_out= (float*)(ws + off);          off += (size_t)Bb * Hh * 4;
  float*          logits = (float*)(ws + off);          off += 1024;
  unsigned int*   syncb  = (unsigned int*)(ws + off);   off += SZ_SY;
  // partial (256*3 x 32*256 fp32 = 25.2 MB) aliases x_bf..g2 (81.8 MB):
  // dead once k_lstm2 completes; pool kernels run strictly after it.
  float*          partial = (float*)ws;

  hipMemsetAsync(syncb, 0, SZ_SY, stream);

  k_embed<<<Bb * Ss, 256, 0, stream>>>(input_ids, embed, x_bf);
  int n4 = (G4 * Hh) / 4;
  int cgrid = (n4 + 255) / 256;
  k_cast<<<cgrid, 256, 0, stream>>>(w_ih0, wb_ih0, n4);
  k_cast<<<cgrid, 256, 0, stream>>>(w_hh0, wb_hh0, n4);
  k_cast<<<cgrid, 256, 0, stream>>>(w_ih1, wb_ih1, n4);
  k_cast<<<cgrid, 256, 0, stream>>>(w_hh1, wb_hh1, n4);

  dim3 ggrid(MR / 128, G4 / 128);
  k_gemm_bt<<<ggrid, 256, 0, stream>>>(x_bf, wb_ih0, g2, b_ih0, b_hh0, MR, G4, Hh);

  k_lstm2<<<2 * NWGL, 128, 0, stream>>>(g2, wb_hh0, wb_ih1, wb_hh1,
                                        b_ih1, b_hh1, hseq1, hseq2, syncb);

  dim3 pgrid(Ss, NCH);
  k_pool_partial<<<pgrid, 256, 0, stream>>>(hseq2, pool_w, partial);
  k_pool_reduce<<<(Bb * Hh) / 256, 256, 0, stream>>>(partial, pool_b, seq_out);
  k_entity_logits<<<Bb, 256, 0, stream>>>(hseq2, seq_out, entity_ids, lin_w, lin_b,
                                          logits, out + 1);
  k_loss<<<1, 64, 0, stream>>>(logits, seq_label, out);
}

// Round 10
// 2289.677 us; speedup vs baseline: 1.9613x; 1.2011x over previous
//
#include <hip/hip_runtime.h>
#include <hip/hip_bf16.h>
#include <stdint.h>

// ---------------- problem constants ----------------
constexpr int Hh  = 768;     // hidden
constexpr int Ss  = 256;     // seq len
constexpr int Bb  = 32;      // batch
constexpr int G4  = 4 * Hh;  // 3072 gate cols
constexpr int MR  = Bb * Ss; // 8192 rows of the big GEMM
constexpr int NWGL = 96;     // LSTM workgroups per layer
constexpr int UPW8 = Hh / NWGL;  // 8 hidden units per WG
constexpr int LCW  = 4 * UPW8;   // 32 gate cols per WG
constexpr int WPAD = Hh + 8;     // padded weight row: stride 1552B == 16B mod 128B
constexpr int CPT  = 256;        // counter dwords per step (16 buckets x 16-dword stride)
constexpr int PB   = 40;         // pool staging row pad
constexpr int NCH  = 3;          // pool n-chunks

typedef short bf16x8 __attribute__((ext_vector_type(8)));
typedef float f32x4  __attribute__((ext_vector_type(4)));
typedef float f32x2  __attribute__((ext_vector_type(2)));
typedef uint32_t u32x4 __attribute__((ext_vector_type(4)));

__device__ __forceinline__ unsigned short f2bf(float f) {
  union { float f; uint32_t u; } v; v.f = f;
  uint32_t u = v.u;
  return (unsigned short)((u + 0x7FFFu + ((u >> 16) & 1u)) >> 16); // RNE
}
__device__ __forceinline__ float bf2f(unsigned short h) {
  union { uint32_t u; float f; } v; v.u = ((uint32_t)h) << 16; return v.f;
}

// ---------------- embedding gather + bf16 cast ----------------
__global__ __launch_bounds__(256) void k_embed(const int* __restrict__ ids,
                                               const float* __restrict__ table,
                                               unsigned short* __restrict__ x_bf) {
  int row = blockIdx.x;                 // b*S+s
  int id  = ids[row];
  const float* src = table + (size_t)id * Hh;
  unsigned short* dst = x_bf + (size_t)row * Hh;
  for (int j = threadIdx.x; j < Hh; j += 256) dst[j] = f2bf(src[j]);
}

// ---------------- fp32 -> bf16 cast (4 elems/thread) ----------------
__global__ __launch_bounds__(256) void k_cast(const float* __restrict__ src,
                                              unsigned short* __restrict__ dst, int n4) {
  int i = blockIdx.x * 256 + threadIdx.x;
  if (i < n4) {
    float4 v = ((const float4*)src)[i];
    uint2 o;
    o.x = (uint32_t)f2bf(v.x) | ((uint32_t)f2bf(v.y) << 16);
    o.y = (uint32_t)f2bf(v.z) | ((uint32_t)f2bf(v.w) << 16);
    ((uint2*)dst)[i] = o;
  }
}

// ---------------- MFMA bf16 TN GEMM -> per-(s,wg) packed pre-gate layout -----
__global__ __launch_bounds__(256) void k_gemm_bt(const unsigned short* __restrict__ A,
                                                 const unsigned short* __restrict__ Bw,
                                                 unsigned short* __restrict__ g2,
                                                 const float* __restrict__ bias1,
                                                 const float* __restrict__ bias2,
                                                 int M, int N, int K) {
  constexpr int BM = 128, BN = 128, BK = 64;
  __shared__ unsigned short Asm[BM * BK];
  __shared__ unsigned short Bsm[BN * BK];
  const int tid = threadIdx.x, lane = tid & 63, wave = tid >> 6;
  const int m0 = blockIdx.x * BM, n0 = blockIdx.y * BN;
  const int wm = (wave & 1) * 64, wn = (wave >> 1) * 64;

  f32x4 acc[4][4];
  #pragma unroll
  for (int a = 0; a < 4; ++a)
    #pragma unroll
    for (int b = 0; b < 4; ++b) acc[a][b] = (f32x4){0.f, 0.f, 0.f, 0.f};

  const int nk = K / BK;
  bf16x8 ar[4], br[4];
  #pragma unroll
  for (int r = 0; r < 4; ++r) {
    int fb = r * 4096 + tid * 16;
    int row = fb >> 7;
    int kb  = (fb >> 4) & 7;
    ar[r] = *(const bf16x8*)(A  + (size_t)(m0 + row) * K + kb * 8);
    br[r] = *(const bf16x8*)(Bw + (size_t)(n0 + row) * K + kb * 8);
  }
  for (int it = 0; it < nk; ++it) {
    __syncthreads();
    #pragma unroll
    for (int r = 0; r < 4; ++r) {
      int fb = r * 4096 + tid * 16;
      int row = fb >> 7;
      int kb  = (fb >> 4) & 7;
      int sb  = kb ^ (row & 7);
      *(bf16x8*)((char*)Asm + row * 128 + sb * 16) = ar[r];
      *(bf16x8*)((char*)Bsm + row * 128 + sb * 16) = br[r];
    }
    __syncthreads();
    if (it + 1 < nk) {
      int k0 = (it + 1) * BK;
      #pragma unroll
      for (int r = 0; r < 4; ++r) {
        int fb = r * 4096 + tid * 16;
        int row = fb >> 7;
        int kb  = (fb >> 4) & 7;
        ar[r] = *(const bf16x8*)(A  + (size_t)(m0 + row) * K + k0 + kb * 8);
        br[r] = *(const bf16x8*)(Bw + (size_t)(n0 + row) * K + k0 + kb * 8);
      }
    }
    #pragma unroll
    for (int kk = 0; kk < 2; ++kk) {
      bf16x8 af[4], bfr[4];
      #pragma unroll
      for (int mi = 0; mi < 4; ++mi) {
        int row = wm + mi * 16 + (lane & 15);
        int kb  = kk * 4 + (lane >> 4);
        int sb  = kb ^ (row & 7);
        af[mi] = *(const bf16x8*)((const char*)Asm + row * 128 + sb * 16);
      }
      #pragma unroll
      for (int ni = 0; ni < 4; ++ni) {
        int row = wn + ni * 16 + (lane & 15);
        int kb  = kk * 4 + (lane >> 4);
        int sb  = kb ^ (row & 7);
        bfr[ni] = *(const bf16x8*)((const char*)Bsm + row * 128 + sb * 16);
      }
      #pragma unroll
      for (int mi = 0; mi < 4; ++mi)
        #pragma unroll
        for (int ni = 0; ni < 4; ++ni)
          acc[mi][ni] = __builtin_amdgcn_mfma_f32_16x16x32_bf16(af[mi], bfr[ni], acc[mi][ni], 0, 0, 0);
    }
  }
  #pragma unroll
  for (int mi = 0; mi < 4; ++mi)
    #pragma unroll
    for (int ni = 0; ni < 4; ++ni)
      #pragma unroll
      for (int r = 0; r < 4; ++r) {
        int row = m0 + wm + mi * 16 + (lane >> 4) * 4 + r;   // = b*256 + s
        int n   = n0 + wn + ni * 16 + (lane & 15);           // gate col
        int bb = row >> 8, ss = row & 255;
        int gi = n / Hh, u = n - gi * Hh;
        int wg = u >> 3, lc = gi * 8 + (u & 7);
        float v = acc[mi][ni][r] + bias1[n] + bias2[n];
        g2[(((size_t)ss * NWGL + wg) * Bb + bb) * LCW + lc] = f2bf(v);
      }
}

// ---------------- fused 2-layer LSTM, wave-specialized, barrier-free ---------
// WGs 0..95: layer-1 (waves 0,1 compute; 2,3 stage+exit).
// WGs 96..191: layer-2 (waves 0,1 = Whh+pointwise; waves 2,3 = Wih producers).
// cnt1/cnt2: 16 buckets x 16-dword stride per step, threshold 12 (6 WGs x 2 waves).
__global__ __launch_bounds__(256) void k_lstm2(
    const unsigned short* __restrict__ g2,
    const unsigned short* __restrict__ w_hh0b,
    const unsigned short* __restrict__ w_ih1b,
    const unsigned short* __restrict__ w_hh1b,
    const float* __restrict__ b_ih1,
    const float* __restrict__ b_hh1,
    unsigned short* __restrict__ hseq1,
    unsigned short* __restrict__ hseq2,
    unsigned int* __restrict__ sync) {
  __shared__ __align__(16) unsigned short Whh[LCW * WPAD];
  __shared__ __align__(16) unsigned short Wih[LCW * WPAD];
  __shared__ __align__(16) unsigned short hbuf[2][16][8];
  __shared__ __align__(16) float gsum[2][2][16][33];   // [slot][bh][row][col]
  __shared__ int prodf[2], consf[2];

  const int wgid = blockIdx.x;
  const int tid = threadIdx.x;
  const int lane = tid & 63, w = tid >> 6;     // w in {0..3}
  unsigned int* cnt1 = sync;
  unsigned int* cnt2 = sync + Ss * CPT;

  const int layer = wgid >= NWGL;
  const int wg = layer ? wgid - NWGL : wgid;
  const int u0 = wg * UPW8;
  const int bkt = wg & 15;

  if (tid < 2) { prodf[tid] = 0; consf[tid] = -1; }

  // stage weight slices into padded LDS rows (all 4 waves)
  {
    const unsigned short* src = layer ? w_hh1b : w_hh0b;
    for (int cch = tid; cch < LCW * 96; cch += 256) {
      int row = cch / 96, kc = cch - row * 96;
      int gi = row >> 3, u = row & 7;
      *(bf16x8*)&Whh[row * WPAD + kc * 8] =
          *(const bf16x8*)(src + (size_t)(gi * Hh + u0 + u) * Hh + kc * 8);
    }
    if (layer) {
      for (int cch = tid; cch < LCW * 96; cch += 256) {
        int row = cch / 96, kc = cch - row * 96;
        int gi = row >> 3, u = row & 7;
        *(bf16x8*)&Wih[row * WPAD + kc * 8] =
            *(const bf16x8*)(w_ih1b + (size_t)(gi * Hh + u0 + u) * Hh + kc * 8);
      }
    }
  }
  __syncthreads();   // the ONLY workgroup barrier

  const int l15 = lane & 15, kq = lane >> 4;
  const bool lo8 = (l15 < 8);

  // ======================= layer-2 producer waves (Wih) =======================
  if (layer && w >= 2) {
    const int bh = w - 2;
    const int brow = bh * 16 + l15;
    for (int t = 0; t < Ss; ++t) {
      // wait for h1[t] (all 96 L1 WGs)
      {
        const unsigned int* b1 = cnt1 + (size_t)t * CPT;
        for (;;) {
          unsigned v = 12;
          if (lane < 16)
            v = __hip_atomic_load(b1 + lane * 16, __ATOMIC_RELAXED, __HIP_MEMORY_SCOPE_AGENT);
          if (__all(v >= 12u)) break;
          __builtin_amdgcn_s_sleep(1);
        }
        asm volatile("" ::: "memory");
      }
      const unsigned short* ap = hseq1 + ((size_t)t * Bb + brow) * Hh + kq * 8;
      bf16x8 areg[24];
      #pragma unroll
      for (int kk = 0; kk < 24; ++kk) areg[kk] = *(const bf16x8*)(ap + kk * 32);
      f32x4 aI[2][2];
      #pragma unroll
      for (int nt = 0; nt < 2; ++nt) {
        aI[nt][0] = (f32x4){0.f,0.f,0.f,0.f}; aI[nt][1] = (f32x4){0.f,0.f,0.f,0.f};
        const int c = nt * 16 + l15;
        #pragma unroll
        for (int kk = 0; kk < 24; ++kk) {
          bf16x8 bfr = *(const bf16x8*)&Wih[c * WPAD + kk * 32 + kq * 8];
          aI[nt][kk & 1] = __builtin_amdgcn_mfma_f32_16x16x32_bf16(areg[kk], bfr, aI[nt][kk & 1], 0, 0, 0);
        }
      }
      // wait for free slot (consumer must have consumed t-2)
      while (__hip_atomic_load(&consf[bh], __ATOMIC_RELAXED, __HIP_MEMORY_SCOPE_WORKGROUP) < t - 1)
        __builtin_amdgcn_s_sleep(0);
      const int par = t & 1;
      #pragma unroll
      for (int nt = 0; nt < 2; ++nt)
        #pragma unroll
        for (int r = 0; r < 4; ++r)
          gsum[par][bh][kq * 4 + r][nt * 16 + l15] = aI[nt][0][r] + aI[nt][1][r];
      __hip_atomic_store(&prodf[bh], t + 1, __ATOMIC_RELEASE, __HIP_MEMORY_SCOPE_WORKGROUP);
    }
    return;
  }
  if (!layer && w >= 2) return;   // L1 helpers done after staging

  // ======================= compute waves (w = 0,1) ============================
  const int bh = w;
  const int brow = bh * 16 + l15;
  const float k1 = lo8 ? 2.f : 1.f;            // nt1 lanes: g (tanh) if lo8 else o
  const float m1 = lo8 ? 2.f : 1.f;
  const float d1 = lo8 ? -1.f : 0.f;

  float bl[2] = {0.f, 0.f};
  if (layer) {
    #pragma unroll
    for (int nt = 0; nt < 2; ++nt) {
      int c = nt * 16 + l15;
      int gcol = (c >> 3) * Hh + u0 + (c & 7);
      bl[nt] = b_ih1[gcol] + b_hh1[gcol];
    }
  }
  unsigned short gc[2][4];
  if (!layer) {
    const unsigned short* grow = g2 + ((size_t)0 * NWGL + wg) * (Bb * LCW);
    #pragma unroll
    for (int nt = 0; nt < 2; ++nt)
      #pragma unroll
      for (int r = 0; r < 4; ++r)
        gc[nt][r] = grow[(bh * 16 + kq * 4 + r) * LCW + nt * 16 + l15];  // t=0
  }
  float cc[4] = {0.f, 0.f, 0.f, 0.f};
  unsigned short* hout = layer ? hseq2 : hseq1;
  unsigned int* mycnt = layer ? cnt2 : cnt1;

  for (int t = 0; t < Ss; ++t) {
    f32x4 aW[2][2];
    #pragma unroll
    for (int nt = 0; nt < 2; ++nt) {
      aW[nt][0] = (f32x4){0.f,0.f,0.f,0.f}; aW[nt][1] = (f32x4){0.f,0.f,0.f,0.f};
    }
    if (t > 0) {
      // wait for own-layer h[t-1] (this wave polls for itself; no barrier)
      {
        const unsigned int* bown = mycnt + (size_t)(t - 1) * CPT;
        for (;;) {
          unsigned v = 12;
          if (lane < 16)
            v = __hip_atomic_load(bown + lane * 16, __ATOMIC_RELAXED, __HIP_MEMORY_SCOPE_AGENT);
          if (__all(v >= 12u)) break;
          __builtin_amdgcn_s_sleep(1);
        }
        asm volatile("" ::: "memory");
      }
      const unsigned short* ap = hout + ((size_t)(t - 1) * Bb + brow) * Hh + kq * 8;
      bf16x8 areg[24];
      #pragma unroll
      for (int kk = 0; kk < 24; ++kk) areg[kk] = *(const bf16x8*)(ap + kk * 32);
      #pragma unroll
      for (int nt = 0; nt < 2; ++nt) {
        const int c = nt * 16 + l15;
        #pragma unroll
        for (int kk = 0; kk < 24; ++kk) {
          bf16x8 bfr = *(const bf16x8*)&Whh[c * WPAD + kk * 32 + kq * 8];
          aW[nt][kk & 1] = __builtin_amdgcn_mfma_f32_16x16x32_bf16(areg[kk], bfr, aW[nt][kk & 1], 0, 0, 0);
        }
      }
    }

    // input-path term: L1 = prefetched pre-gates; L2 = LDS partial from producers
    float gin[2][4];
    if (layer) {
      while (__hip_atomic_load(&prodf[bh], __ATOMIC_ACQUIRE, __HIP_MEMORY_SCOPE_WORKGROUP) < t + 1)
        __builtin_amdgcn_s_sleep(0);
      const int par = t & 1;
      #pragma unroll
      for (int nt = 0; nt < 2; ++nt)
        #pragma unroll
        for (int r = 0; r < 4; ++r)
          gin[nt][r] = gsum[par][bh][kq * 4 + r][nt * 16 + l15] + bl[nt];
      __hip_atomic_store(&consf[bh], t, __ATOMIC_RELEASE, __HIP_MEMORY_SCOPE_WORKGROUP);
    } else {
      #pragma unroll
      for (int nt = 0; nt < 2; ++nt)
        #pragma unroll
        for (int r = 0; r < 4; ++r)
          gin[nt][r] = bf2f(gc[nt][r]);
    }

    // ---- activations ----
    float act0[4], act1[4];
    #pragma unroll
    for (int r = 0; r < 4; ++r) {
      float v0 = aW[0][0][r] + aW[0][1][r] + gin[0][r];
      act0[r] = 1.f / (1.f + __expf(-v0));                   // i or f: sigmoid
      float v1 = aW[1][0][r] + aW[1][1][r] + gin[1][r];
      act1[r] = m1 / (1.f + __expf(-k1 * v1)) + d1;          // g: tanh, o: sigmoid
    }

    // ---- pointwise c/h via lane^8 shuffle ----
    #pragma unroll
    for (int r = 0; r < 4; ++r) {
      float p0 = __shfl_xor(act0[r], 8);
      float p1 = __shfl_xor(act1[r], 8);
      float iv = lo8 ? act0[r] : p0;
      float fv = lo8 ? p0 : act0[r];
      float gv = lo8 ? act1[r] : p1;
      float ov = lo8 ? p1 : act1[r];
      float cn = fv * cc[r] + iv * gv;
      cc[r] = cn;
      float e = __expf(-2.f * cn);
      float hv = ov * (1.f - e) / (1.f + e);
      if (lo8) hbuf[w][kq * 4 + r][l15] = f2bf(hv);
    }
    asm volatile("s_waitcnt lgkmcnt(0)" ::: "memory");   // wave's hbuf writes done

    // ---- publish h (16 lanes x 16B); vmcnt; per-wave bucket add ----
    if (lane < 16) {
      const unsigned long long* hb = (const unsigned long long*)&hbuf[w][lane][0];
      unsigned long long x0 = hb[0], x1 = hb[1];
      unsigned long long* hp =
          (unsigned long long*)(hout + ((size_t)t * Bb + (bh * 16 + lane)) * Hh + u0);
      __hip_atomic_store(hp + 0, x0, __ATOMIC_RELAXED, __HIP_MEMORY_SCOPE_AGENT);
      __hip_atomic_store(hp + 1, x1, __ATOMIC_RELAXED, __HIP_MEMORY_SCOPE_AGENT);
    }
    asm volatile("s_waitcnt vmcnt(0)" ::: "memory");     // h acked at LLC
    if (lane == 0) {
      unsigned int* cp = mycnt + (size_t)t * CPT + bkt * 16;
      (void)__hip_atomic_fetch_add(cp, 1u, __ATOMIC_RELAXED, __HIP_MEMORY_SCOPE_AGENT);
    }

    // ---- prefetch next-step pre-gates (off the publish path) ----
    if (!layer && t + 1 < Ss) {
      const unsigned short* grow = g2 + ((size_t)(t + 1) * NWGL + wg) * (Bb * LCW);
      #pragma unroll
      for (int nt = 0; nt < 2; ++nt)
        #pragma unroll
        for (int r = 0; r < 4; ++r)
          gc[nt][r] = grow[(bh * 16 + kq * 4 + r) * LCW + nt * 16 + l15];
    }
  }
}

// ---------------- pool partial, n-split: grid (Ss, NCH) ----------------------
__global__ __launch_bounds__(256) void k_pool_partial(const unsigned short* __restrict__ hseq2,
                                                      const float* __restrict__ pw,
                                                      float* __restrict__ partial) {
  __shared__ __align__(16) unsigned short osm[Hh * PB];
  const int tid = threadIdx.x;
  const int s = blockIdx.x, nc = blockIdx.y;
  for (int b = 0; b < Bb; ++b) {
    const unsigned short* src = hseq2 + ((size_t)s * Bb + b) * Hh;
    for (int k = tid; k < Hh; k += 256) osm[k * PB + b] = src[k];
  }
  __syncthreads();
  f32x2 acc[16];
  #pragma unroll
  for (int bp = 0; bp < 16; ++bp) acc[bp] = (f32x2){0.f, 0.f};
  const float* pbase = pw + (size_t)s * Hh * Hh + nc * 256 + tid;
  #pragma unroll 4
  for (int k = 0; k < Hh; ++k) {
    float wv = pbase[(size_t)k * Hh];
    u32x4 h0 = *(const u32x4*)&osm[k * PB + 0];
    u32x4 h1 = *(const u32x4*)&osm[k * PB + 8];
    u32x4 h2 = *(const u32x4*)&osm[k * PB + 16];
    u32x4 h3 = *(const u32x4*)&osm[k * PB + 24];
    uint32_t hw[16] = {h0[0],h0[1],h0[2],h0[3], h1[0],h1[1],h1[2],h1[3],
                       h2[0],h2[1],h2[2],h2[3], h3[0],h3[1],h3[2],h3[3]};
    #pragma unroll
    for (int bp = 0; bp < 16; ++bp) {
      uint32_t pv = hw[bp];
      f32x2 ov;
      ov.x = __uint_as_float(pv << 16);
      ov.y = __uint_as_float(pv & 0xffff0000u);
      acc[bp] += ov * wv;
    }
  }
  float* pout = partial + (size_t)(s * NCH + nc) * (Bb * 256);
  #pragma unroll
  for (int bp = 0; bp < 16; ++bp) {
    pout[(size_t)(bp * 2 + 0) * 256 + tid] = acc[bp].x;
    pout[(size_t)(bp * 2 + 1) * 256 + tid] = acc[bp].y;
  }
}

__global__ __launch_bounds__(256) void k_pool_reduce(const float* __restrict__ partial,
                                                     const float* __restrict__ pool_b,
                                                     float* __restrict__ seq_out) {
  int i = blockIdx.x * 256 + threadIdx.x;   // b*768+n
  int b = i / Hh, n = i - b * Hh;
  int nchunk = n >> 8, nn = n & 255;
  float acc = pool_b[n];
  const float* p = partial + (size_t)nchunk * (Bb * 256) + b * 256 + nn;
  #pragma unroll 8
  for (int t = 0; t < Ss; ++t) acc += p[(size_t)t * NCH * (Bb * 256)];
  seq_out[i] = acc;
}

// ---------------- entity masked max + logits ----------------
__global__ __launch_bounds__(256) void k_entity_logits(const unsigned short* __restrict__ hseq2,
                                                       const float* __restrict__ seq_out,
                                                       const int* __restrict__ entity_ids,
                                                       const float* __restrict__ lin_w,
                                                       const float* __restrict__ lin_b,
                                                       float* __restrict__ logits_ws,
                                                       float* __restrict__ dlogits) {
  const int b = blockIdx.x, tid = threadIdx.x;
  float m0 = -1e30f, m1 = -1e30f, m2 = -1e30f;
  for (int s = 0; s < Ss; ++s) {
    bool e = entity_ids[b * Ss + s] == 1;
    const unsigned short* row = hseq2 + ((size_t)s * Bb + b) * Hh;
    float v0 = bf2f(row[tid]);
    float v1 = bf2f(row[256 + tid]);
    float v2 = bf2f(row[512 + tid]);
    v0 = e ? v0 : 0.f; v1 = e ? v1 : 0.f; v2 = e ? v2 : 0.f;
    m0 = fmaxf(m0, v0); m1 = fmaxf(m1, v1); m2 = fmaxf(m2, v2);
  }
  __shared__ float red[512];
  float p0 = 0.f, p1 = 0.f;
  float mm[3] = {m0, m1, m2};
  #pragma unroll
  for (int j = 0; j < 3; ++j) {
    int n = j * 256 + tid;
    float bo = fmaxf(mm[j], seq_out[b * Hh + n]);
    p0 += bo * lin_w[n * 2 + 0];
    p1 += bo * lin_w[n * 2 + 1];
  }
  red[tid] = p0; red[256 + tid] = p1;
  __syncthreads();
  for (int off = 128; off > 0; off >>= 1) {
    if (tid < off) { red[tid] += red[tid + off]; red[256 + tid] += red[256 + tid + off]; }
    __syncthreads();
  }
  if (tid == 0) {
    float l0 = red[0] + lin_b[0], l1 = red[256] + lin_b[1];
    logits_ws[b * 2] = l0; logits_ws[b * 2 + 1] = l1;
    dlogits[b * 2] = l0;  dlogits[b * 2 + 1] = l1;
  }
}

// ---------------- BCEWithLogits mean loss ----------------
__global__ void k_loss(const float* __restrict__ logits, const int* __restrict__ lab,
                       float* __restrict__ dout) {
  __shared__ float red[64];
  int i = threadIdx.x;
  float l = logits[i];
  float y = (float)lab[i];
  red[i] = fmaxf(l, 0.f) - l * y + log1pf(__expf(-fabsf(l)));
  __syncthreads();
  for (int off = 32; off > 0; off >>= 1) {
    if (i < off) red[i] += red[i + off];
    __syncthreads();
  }
  if (i == 0) dout[0] = red[0] * (1.f / 64.f);
}

// ---------------- launcher ----------------
extern "C" void kernel_launch(void* const* d_in, const int* in_sizes, int n_in,
                              void* d_out, int out_size, void* d_ws, size_t ws_size,
                              hipStream_t stream) {
  const int*   input_ids  = (const int*)d_in[0];
  const int*   seq_label  = (const int*)d_in[3];
  const int*   entity_ids = (const int*)d_in[4];
  const float* embed      = (const float*)d_in[5];
  const float* w_ih0      = (const float*)d_in[6];
  const float* w_hh0      = (const float*)d_in[7];
  const float* b_ih0      = (const float*)d_in[8];
  const float* b_hh0      = (const float*)d_in[9];
  const float* w_ih1      = (const float*)d_in[10];
  const float* w_hh1      = (const float*)d_in[11];
  const float* b_ih1      = (const float*)d_in[12];
  const float* b_hh1      = (const float*)d_in[13];
  const float* pool_w     = (const float*)d_in[14];
  const float* pool_b     = (const float*)d_in[15];
  const float* lin_w      = (const float*)d_in[16];
  const float* lin_b      = (const float*)d_in[17];
  float* out = (float*)d_out;

  const size_t SZ_XO = (size_t)Bb * Ss * Hh * 2;   // 12.58 MB
  const size_t SZ_W  = (size_t)G4 * Hh * 2;        //  4.72 MB
  const size_t SZ_G  = (size_t)Bb * Ss * G4 * 2;   // 50.33 MB
  const size_t SZ_SY = (size_t)2 * Ss * CPT * 4;   // 512 KB counters
  char* ws = (char*)d_ws;
  size_t off = 0;
  unsigned short* x_bf   = (unsigned short*)(ws + off); off += SZ_XO;
  unsigned short* wb_ih0 = (unsigned short*)(ws + off); off += SZ_W;
  unsigned short* wb_hh0 = (unsigned short*)(ws + off); off += SZ_W;
  unsigned short* wb_ih1 = (unsigned short*)(ws + off); off += SZ_W;
  unsigned short* wb_hh1 = (unsigned short*)(ws + off); off += SZ_W;
  unsigned short* g2     = (unsigned short*)(ws + off); off += SZ_G;
  unsigned short* hseq1  = (unsigned short*)(ws + off); off += SZ_XO;
  unsigned short* hseq2  = (unsigned short*)(ws + off); off += SZ_XO;
  float*          seq_out= (float*)(ws + off);          off += (size_t)Bb * Hh * 4;
  float*          logits = (float*)(ws + off);          off += 1024;
  unsigned int*   syncb  = (unsigned int*)(ws + off);   off += SZ_SY;
  float*          partial = (float*)ws;  // aliases dead x_bf..g2 after k_lstm2

  hipMemsetAsync(syncb, 0, SZ_SY, stream);

  k_embed<<<Bb * Ss, 256, 0, stream>>>(input_ids, embed, x_bf);
  int n4 = (G4 * Hh) / 4;
  int cgrid = (n4 + 255) / 256;
  k_cast<<<cgrid, 256, 0, stream>>>(w_ih0, wb_ih0, n4);
  k_cast<<<cgrid, 256, 0, stream>>>(w_hh0, wb_hh0, n4);
  k_cast<<<cgrid, 256, 0, stream>>>(w_ih1, wb_ih1, n4);
  k_cast<<<cgrid, 256, 0, stream>>>(w_hh1, wb_hh1, n4);

  dim3 ggrid(MR / 128, G4 / 128);
  k_gemm_bt<<<ggrid, 256, 0, stream>>>(x_bf, wb_ih0, g2, b_ih0, b_hh0, MR, G4, Hh);

  k_lstm2<<<2 * NWGL, 256, 0, stream>>>(g2, wb_hh0, wb_ih1, wb_hh1,
                                        b_ih1, b_hh1, hseq1, hseq2, syncb);

  dim3 pgrid(Ss, NCH);
  k_pool_partial<<<pgrid, 256, 0, stream>>>(hseq2, pool_w, partial);
  k_pool_reduce<<<(Bb * Hh) / 256, 256, 0, stream>>>(partial, pool_b, seq_out);
  k_entity_logits<<<Bb, 256, 0, stream>>>(hseq2, seq_out, entity_ids, lin_w, lin_b,
                                          logits, out + 1);
  k_loss<<<1, 64, 0, stream>>>(logits, seq_label, out);
}